// Round 1
// 580.266 us; speedup vs baseline: 1.0020x; 1.0020x over previous
//
#include <hip/hip_runtime.h>
#include <math.h>

// Soft-Viterbi structured decoding: B=32, T=512, N=128, fp32.
// Linear-space formulation, ONE barrier + ONE LDS round trip per step,
// no transcendentals on the critical path.
//
// This revision: the per-step __syncthreads() (which compiles to
// s_waitcnt vmcnt(0) lgkmcnt(0) + s_barrier, draining the per-step global
// alpha-stash store AND the emission prefetch every iteration) is replaced
// by a raw s_barrier preceded by s_waitcnt lgkmcnt(0) ONLY. Global stores
// become fire-and-forget; prefetches stay in flight across barriers.
// A single vmcnt(0) drain between forward and backward guarantees the
// backward pass observes the forward alpha stash (same-wave vmem ops are
// not address-ordered without a waitcnt).
//
// Forward:  alpha~_t = d_t * r_{t-1} * Z_raw,t ;  Z_raw,t[n] = sum_p T[p,n] alpha~_{t-1}[p]
//           d_t = exp(em_t) (prefetched 2 steps ahead, off-chain)
//           r_{t-1} = 1/alpha~_{t-1}[0]  (from broadcast read of ebuf[0], off-chain)
//           alpha~_t stashed into out[b][t] (scratch-in-output), r_t in LDS sarr[].
// Backward: p_t[m] = alpha~_t[m] * sum_n q[n] T[m,n],
//           q[n] = p_{t+1}[n] * d_{t+1}[n] * r_t / alpha~_{t+1}[n]  (all prefetched off-chain).
//
// Layout: 4 waves; wave w owns states [32w,32w+32); lane pair (si=lane>>1, ph=lane&1)
// computes one state's full 128-dot: 64 FMA over half [64ph,64ph+64) + shfl_xor(1) combine.
// e/q exchange ping-pongs ubuf[2][128] so one barrier/step is WAR/RAW-safe.

#define TT 512
#define BB 32
#define NN 128
#define EPSC 1e-10f
#define TINY 1e-33f

// Raw workgroup barrier with LDS-only drain: does NOT wait on vmcnt, so
// global stores/loads in flight are not serialized against the barrier.
__device__ __forceinline__ void bar_lds() {
  __builtin_amdgcn_sched_barrier(0);
  asm volatile("s_waitcnt lgkmcnt(0)" ::: "memory");
  __builtin_amdgcn_s_barrier();
  __builtin_amdgcn_sched_barrier(0);
}

__global__ __launch_bounds__(256, 1)
void soft_viterbi_kernel(const float* __restrict__ trans,
                         const float* __restrict__ emis,
                         const float* __restrict__ prior,
                         float* __restrict__ out) {
  const int b    = blockIdx.x;
  const int tid  = threadIdx.x;
  const int w    = tid >> 6;
  const int lane = tid & 63;
  const int si   = lane >> 1;        // state within chunk
  const int ph   = lane & 1;         // which half of the 128-range this lane sums
  const int n_own = 32 * w + si;     // owned state
  const int pbase = 64 * ph;         // start of this lane's 64-element range

  __shared__ __align__(16) float ubuf[2][NN];  // ping-pong alpha~ / q exchange
  __shared__ __align__(16) float sarr[TT];     // sarr[t] = r_t = 1/alpha~_t[0]
  __shared__ __align__(16) float red[NN];      // rowsum, then reduction scratch

  const float* emb = emis + (size_t)b * TT * NN + n_own;  // per-lane emission column
  float* outb = out + (size_t)b * TT * NN;

  // ---- issue early global loads (prior, em[0..3]) ----
  float pr  = fmaxf(prior[n_own], EPSC);
  float em0 = emb[0];
  float eA  = emb[1 * NN];
  float eB  = emb[2 * NN];
  float eC  = emb[3 * NN];

  // ---- row sums of clipped transition ----
  if (tid < NN) {
    const float4* row = (const float4*)(trans + tid * NN);
    float s = 0.f;
    #pragma unroll 8
    for (int j = 0; j < NN / 4; ++j) {
      float4 v = row[j];
      s += fmaxf(v.x, EPSC) + fmaxf(v.y, EPSC) + fmaxf(v.z, EPSC) + fmaxf(v.w, EPSC);
    }
    red[tid] = s;
  }
  __syncthreads();

  // ---- forward fragment: tf[k] = Tn[pbase+k][n_own] ----
  float tf[64];
  #pragma unroll
  for (int k = 0; k < 64; ++k) {
    const int p = pbase + k;
    tf[k] = fmaxf(trans[p * NN + n_own], EPSC) / red[p];
  }
  // ---- backward fragment: tb[k] = Tn[n_own][pbase+k] ----
  float tb[64];
  {
    const float inv = 1.0f / red[n_own];
    const float4* r = (const float4*)(trans + n_own * NN + pbase);
    #pragma unroll
    for (int k = 0; k < 16; ++k) {
      float4 v = r[k];
      tb[4*k+0] = fmaxf(v.x, EPSC) * inv;
      tb[4*k+1] = fmaxf(v.y, EPSC) * inv;
      tb[4*k+2] = fmaxf(v.z, EPSC) * inv;
      tb[4*k+3] = fmaxf(v.w, EPSC) * inv;
    }
  }

  // ---- prior normalization (chunk sum via masked butterfly, combine via red[]) ----
  float vv = ph ? 0.f : pr;
  #pragma unroll
  for (int m = 1; m < 64; m <<= 1) vv += __shfl_xor(vv, m, 64);
  __syncthreads();                 // all tf/tb reads of red[] complete
  if (lane == 0) red[w] = vv;
  __syncthreads();
  const float psum = (red[0] + red[1]) + (red[2] + red[3]);

  // ---- u0 = alpha~_0 ----
  float an = (pr / psum) * __expf(em0);
  if (ph == 0) { ubuf[0][n_own] = an; outb[n_own] = an; }  // stash row 0
  float d_cur = __expf(eA);        // d_1
  float em_h1 = eB;                // em[2]
  float em_h2 = eC;                // em[3]
  float d_last = d_cur;
  bar_lds();                       // publish ubuf[0] (no vmcnt drain)

  // ================= forward =================
  for (int t = 1; t < TT; ++t) {
    const float* rb = ubuf[(t - 1) & 1];
    const float r0 = rb[0];                       // broadcast read, lands early
    const float4* rb4 = (const float4*)(rb + pbase);
    float a0 = 0.f, a1 = 0.f, a2 = 0.f, a3 = 0.f;
    #pragma unroll
    for (int j = 0; j < 16; ++j) {
      float4 ev = rb4[j];
      a0 = fmaf(ev.x, tf[4*j+0], a0);
      a1 = fmaf(ev.y, tf[4*j+1], a1);
      a2 = fmaf(ev.z, tf[4*j+2], a2);
      a3 = fmaf(ev.w, tf[4*j+3], a3);
    }
    const float rinv = 1.0f / r0;                 // off-chain (r0 early)
    const float dsc  = d_cur * rinv;
    if (t == TT - 1) d_last = d_cur;              // keep d_{T-1} for backward init
    d_cur = __expf(em_h1);                        // d_{t+1}, off-chain
    em_h1 = em_h2;
    const int tpre = (t + 3 < TT) ? (t + 3) : (TT - 1);
    em_h2 = emb[tpre * NN];                       // prefetch em[t+3], stays in flight
    float z = (a0 + a1) + (a2 + a3);
    z += __shfl_xor(z, 1, 64);                    // combine halves (DPP neighbor swap)
    an = dsc * z;                                 // alpha~_t[n_own]
    if (ph == 0) {
      ubuf[t & 1][n_own] = an;
      if (t < TT - 1) outb[t * NN + n_own] = an;  // fire-and-forget stash
    }
    if (tid == 0) sarr[t - 1] = rinv;             // r_{t-1}
    bar_lds();                                    // LDS-only drain + barrier
  }

  // ================= final softmax =================
  float v2 = ph ? 0.f : an;
  #pragma unroll
  for (int m = 1; m < 64; m <<= 1) v2 += __shfl_xor(v2, m, 64);
  if (lane == 0) red[w] = v2;
  __syncthreads();
  const float total = (red[0] + red[1]) + (red[2] + red[3]);
  float p_cur = an / total;                       // p_{T-1}
  if (ph == 0) outb[(TT - 1) * NN + n_own] = p_cur;

  // One-time drain: make ALL forward alpha-stash stores visible before the
  // backward pass re-reads them (same-wave vmem ops are not address-ordered
  // without a waitcnt). This replaces the per-step drains we removed.
  asm volatile("s_waitcnt vmcnt(0)" ::: "memory");

  // ---- backward pipeline init (issue loads early) ----
  float ec_cur = outb[(TT - 2) * NN + n_own];     // alpha~_{T-2}
  float ec_h   = outb[(TT - 3) * NN + n_own];     // alpha~_{T-3}
  float em_b1  = emb[(TT - 2) * NN];              // em[T-2]
  float em_b2  = emb[(TT - 3) * NN];              // em[T-3]
  float g_cur  = d_last * sarr[TT - 2] / fmaxf(an, TINY);  // d_{T-1} r_{T-2} / alpha~_{T-1}

  // ================= backward =================
  for (int t = TT - 2; t >= 0; --t) {
    const float q = p_cur * g_cur;
    if (ph == 0) ubuf[t & 1][n_own] = q;
    // off-chain prep for iter t-1:
    const float sr = sarr[(t > 0) ? (t - 1) : 0];
    const float g_next = __expf(em_b1) * sr / fmaxf(ec_cur, TINY);
    em_b1 = em_b2;
    const int tp = (t >= 2) ? (t - 2) : 0;
    em_b2 = emb[tp * NN];
    bar_lds();                                    // LDS-only drain + barrier
    const float4* qb4 = (const float4*)(ubuf[t & 1] + pbase);
    float a0 = 0.f, a1 = 0.f, a2 = 0.f, a3 = 0.f;
    #pragma unroll
    for (int j = 0; j < 16; ++j) {
      float4 qv = qb4[j];
      a0 = fmaf(qv.x, tb[4*j+0], a0);
      a1 = fmaf(qv.y, tb[4*j+1], a1);
      a2 = fmaf(qv.z, tb[4*j+2], a2);
      a3 = fmaf(qv.w, tb[4*j+3], a3);
    }
    float s = (a0 + a1) + (a2 + a3);
    s += __shfl_xor(s, 1, 64);
    p_cur = ec_cur * s;                           // p_t
    if (ph == 0) outb[t * NN + n_own] = p_cur;    // fire-and-forget result
    g_cur  = g_next;
    ec_cur = ec_h;                                // alpha~_{t-1}
    ec_h   = outb[tp * NN + n_own];               // prefetch alpha~_{t-2}
  }
}

extern "C" void kernel_launch(void* const* d_in, const int* in_sizes, int n_in,
                              void* d_out, int out_size, void* d_ws, size_t ws_size,
                              hipStream_t stream) {
  (void)in_sizes; (void)n_in; (void)d_ws; (void)ws_size; (void)out_size;
  const float* trans = (const float*)d_in[0];
  const float* emis  = (const float*)d_in[1];
  const float* prior = (const float*)d_in[2];
  float* out = (float*)d_out;
  soft_viterbi_kernel<<<dim3(BB), dim3(256), 0, stream>>>(trans, emis, prior, out);
}